// Round 1
// baseline (408.428 us; speedup 1.0000x reference)
//
#include <hip/hip_runtime.h>
#include <stdint.h>

// Problem constants (from reference): B=32, N=16384, D=64, fp32 in/out.
#define Bn  32
#define Nn  16384
#define Dn  64
#define TILE 64                         // rows per wave-tile (K for MFMA rank-update)
#define SB  32                          // blocks per batch
#define ROWS_PER_BLOCK (Nn / SB)        // 512
#define ROWS_PER_WAVE  (ROWS_PER_BLOCK / 4)   // 128
#define TILES_PER_WAVE (ROWS_PER_WAVE / TILE) // 2
#define LDT 72                          // bf16 row stride (64 + 8 pad; 144 B, 16B-aligned)

typedef __attribute__((ext_vector_type(8))) short bf16x8;  // MFMA A/B frag (8 bf16)
typedef __attribute__((ext_vector_type(4))) float f32x4;   // MFMA C/D frag
typedef __attribute__((ext_vector_type(4))) unsigned int u32x4;

static __device__ __forceinline__ unsigned int f2bf(float f) {
    // round-to-nearest-even fp32 -> bf16 (values here are finite, no NaN)
    unsigned int u = __float_as_uint(f);
    return (u + 0x7fffu + ((u >> 16) & 1u)) >> 16;
}

// ---------------------------------------------------------------------------
// Kernel 1: per-block partial of ctx^T[e][d] = sum_t v[t][e] * softmax(k)[t][d]
// Wave-autonomous (no __syncthreads in main loop). MFMA orientation:
//   A[m=e][k=t] = vT[e][t], B[k=t][n=d] = knT[d][t], D[m=e][n=d] = ctxT.
// ---------------------------------------------------------------------------
__global__ __launch_bounds__(256) void ctx_partial_kernel(
        const float* __restrict__ K, const float* __restrict__ V,
        float* __restrict__ partial) {
    __shared__ unsigned short smem[4 * 2 * Dn * LDT];   // 73728 B; aliased for reduce
    const int tid  = threadIdx.x;
    const int wid  = tid >> 6, lane = tid & 63;
    const int b    = blockIdx.x / SB, s = blockIdx.x % SB;
    const int l15  = lane & 15, quad = lane >> 4;

    unsigned short* knT = smem + (wid * 2 + 0) * Dn * LDT;  // [d][t] bf16
    unsigned short* vT  = smem + (wid * 2 + 1) * Dn * LDT;  // [e][t] bf16

    const float* Kb = K + ((size_t)b * Nn) * Dn;
    const float* Vb = V + ((size_t)b * Nn) * Dn;
    const int row0 = s * ROWS_PER_BLOCK + wid * ROWS_PER_WAVE;

    f32x4 acc[4][4];
    #pragma unroll
    for (int i = 0; i < 4; ++i)
        #pragma unroll
        for (int j = 0; j < 4; ++j) acc[i][j] = (f32x4)(0.0f);

    for (int t = 0; t < TILES_PER_WAVE; ++t) {
        const int rbase = row0 + t * TILE;

        // ---- V row (lane = row): load, cast, transposed scatter vT[e][lane]
        {
            const float4* vr = (const float4*)(Vb + (size_t)(rbase + lane) * Dn);
            float4 v4[16];
            #pragma unroll
            for (int j = 0; j < 16; ++j) v4[j] = vr[j];
            #pragma unroll
            for (int j = 0; j < 16; ++j) {
                vT[(4*j+0)*LDT + lane] = (unsigned short)f2bf(v4[j].x);
                vT[(4*j+1)*LDT + lane] = (unsigned short)f2bf(v4[j].y);
                vT[(4*j+2)*LDT + lane] = (unsigned short)f2bf(v4[j].z);
                vT[(4*j+3)*LDT + lane] = (unsigned short)f2bf(v4[j].w);
            }
        }
        // ---- K row (lane = row): register softmax over D, scatter knT[d][lane]
        {
            const float4* kr = (const float4*)(Kb + (size_t)(rbase + lane) * Dn);
            float4 k4[16];
            #pragma unroll
            for (int j = 0; j < 16; ++j) k4[j] = kr[j];
            float m = -1e30f;
            #pragma unroll
            for (int j = 0; j < 16; ++j)
                m = fmaxf(m, fmaxf(fmaxf(k4[j].x, k4[j].y), fmaxf(k4[j].z, k4[j].w)));
            float sum = 0.0f;
            #pragma unroll
            for (int j = 0; j < 16; ++j) {
                k4[j].x = __expf(k4[j].x - m);
                k4[j].y = __expf(k4[j].y - m);
                k4[j].z = __expf(k4[j].z - m);
                k4[j].w = __expf(k4[j].w - m);
                sum += k4[j].x + k4[j].y + k4[j].z + k4[j].w;
            }
            const float inv = 1.0f / sum;
            #pragma unroll
            for (int j = 0; j < 16; ++j) {
                knT[(4*j+0)*LDT + lane] = (unsigned short)f2bf(k4[j].x * inv);
                knT[(4*j+1)*LDT + lane] = (unsigned short)f2bf(k4[j].y * inv);
                knT[(4*j+2)*LDT + lane] = (unsigned short)f2bf(k4[j].z * inv);
                knT[(4*j+3)*LDT + lane] = (unsigned short)f2bf(k4[j].w * inv);
            }
        }
        // ---- MFMA rank-64 update (K of tile = 64 rows -> 2 k-steps of 32)
        #pragma unroll
        for (int ks = 0; ks < 2; ++ks) {
            const int koff = ks * 32 + quad * 8;   // bf16 elements
            bf16x8 af[4], bfr[4];
            #pragma unroll
            for (int et = 0; et < 4; ++et)
                af[et] = *(const bf16x8*)(vT + (et*16 + l15)*LDT + koff);
            #pragma unroll
            for (int dt = 0; dt < 4; ++dt)
                bfr[dt] = *(const bf16x8*)(knT + (dt*16 + l15)*LDT + koff);
            #pragma unroll
            for (int et = 0; et < 4; ++et)
                #pragma unroll
                for (int dt = 0; dt < 4; ++dt)
                    acc[et][dt] = __builtin_amdgcn_mfma_f32_16x16x32_bf16(
                        af[et], bfr[dt], acc[et][dt], 0, 0, 0);
        }
    }

    // ---- block reduce (4 waves -> 1) via aliased LDS, write one partial/block
    __syncthreads();
    float* red = (float*)smem;          // 2 * 4096 floats = 32 KB (fits in 73.7 KB)
    if (wid < 2) {
        float* buf = red + wid * 4096;
        #pragma unroll
        for (int et = 0; et < 4; ++et)
            #pragma unroll
            for (int dt = 0; dt < 4; ++dt)
                #pragma unroll
                for (int i = 0; i < 4; ++i)
                    buf[(et*16 + quad*4 + i)*64 + dt*16 + l15] = acc[et][dt][i];
    }
    __syncthreads();
    if (wid >= 2) {
        float* buf = red + (wid - 2) * 4096;
        #pragma unroll
        for (int et = 0; et < 4; ++et)
            #pragma unroll
            for (int dt = 0; dt < 4; ++dt)
                #pragma unroll
                for (int i = 0; i < 4; ++i)
                    buf[(et*16 + quad*4 + i)*64 + dt*16 + l15] += acc[et][dt][i];
    }
    __syncthreads();
    f32x4* pout = (f32x4*)(partial + (size_t)blockIdx.x * 4096);
    const f32x4* b0 = (const f32x4*)red;
    const f32x4* b1 = (const f32x4*)(red + 4096);
    #pragma unroll
    for (int c = 0; c < 4; ++c) {
        int i4 = c * 256 + tid;
        pout[i4] = b0[i4] + b1[i4];
    }
}

// ---------------------------------------------------------------------------
// Kernel 2: ctxT[b][4096] = sum over SB partials (coalesced)
// ---------------------------------------------------------------------------
__global__ __launch_bounds__(256) void ctx_reduce_kernel(
        const float* __restrict__ partial, float* __restrict__ ctx) {
    const int g = blockIdx.x * 256 + threadIdx.x;   // 0 .. 32*4096-1
    const int b = g >> 12, i = g & 4095;
    const float* p = partial + ((size_t)b * SB) * 4096 + i;
    float ssum = 0.0f;
    #pragma unroll 8
    for (int w = 0; w < SB; ++w) ssum += p[(size_t)w * 4096];
    ctx[g] = ssum;
}

// ---------------------------------------------------------------------------
// Kernel 3: out[r][e] = sum_d softmax(q)[r][d] * ctx[d][e]
//   A[m=r][k=d] = qn row-major (no transpose!), B[k=d][n=e] = ctxT_s[e][d].
// ---------------------------------------------------------------------------
__global__ __launch_bounds__(256) void attn_out_kernel(
        const float* __restrict__ Q, const float* __restrict__ ctx,
        float* __restrict__ out) {
    __shared__ unsigned short ctxT_s[Dn * LDT];       // 9216 B, block-shared
    __shared__ unsigned short qbuf[4][TILE * LDT];    // 36864 B, per-wave
    const int tid  = threadIdx.x;
    const int wid  = tid >> 6, lane = tid & 63;
    const int b    = blockIdx.x / SB, s = blockIdx.x % SB;
    const int l15  = lane & 15, quad = lane >> 4;

    // ctx^T (stored [e][d] in ws) -> bf16 LDS, coalesced
    {
        const f32x4* c4 = (const f32x4*)(ctx + (size_t)b * 4096);
        #pragma unroll
        for (int c = 0; c < 4; ++c) {
            int i4 = c * 256 + tid;
            f32x4 v = c4[i4];
            int e = (i4 * 4) >> 6, d0 = (i4 * 4) & 63;
            unsigned int lo = f2bf(v.x) | (f2bf(v.y) << 16);
            unsigned int hi = f2bf(v.z) | (f2bf(v.w) << 16);
            *(uint2*)(ctxT_s + e * LDT + d0) = make_uint2(lo, hi);
        }
    }
    __syncthreads();

    unsigned short* qb = qbuf[wid];
    const int row0 = s * ROWS_PER_BLOCK + wid * ROWS_PER_WAVE;

    for (int t = 0; t < TILES_PER_WAVE; ++t) {
        const int rbase = row0 + t * TILE;
        // ---- Q row (lane = row): register softmax, row-major bf16 store
        {
            const float4* qr = (const float4*)(Q + ((size_t)b * Nn + rbase + lane) * Dn);
            float4 q4[16];
            #pragma unroll
            for (int j = 0; j < 16; ++j) q4[j] = qr[j];
            float m = -1e30f;
            #pragma unroll
            for (int j = 0; j < 16; ++j)
                m = fmaxf(m, fmaxf(fmaxf(q4[j].x, q4[j].y), fmaxf(q4[j].z, q4[j].w)));
            float sum = 0.0f;
            #pragma unroll
            for (int j = 0; j < 16; ++j) {
                q4[j].x = __expf(q4[j].x - m);
                q4[j].y = __expf(q4[j].y - m);
                q4[j].z = __expf(q4[j].z - m);
                q4[j].w = __expf(q4[j].w - m);
                sum += q4[j].x + q4[j].y + q4[j].z + q4[j].w;
            }
            const float inv = 1.0f / sum;
            unsigned int us[32];
            #pragma unroll
            for (int j = 0; j < 16; ++j) {
                us[2*j]   = f2bf(q4[j].x * inv) | (f2bf(q4[j].y * inv) << 16);
                us[2*j+1] = f2bf(q4[j].z * inv) | (f2bf(q4[j].w * inv) << 16);
            }
            u32x4* dst = (u32x4*)(qb + lane * LDT);
            #pragma unroll
            for (int c = 0; c < 8; ++c) {
                u32x4 w = { us[4*c], us[4*c+1], us[4*c+2], us[4*c+3] };
                dst[c] = w;
            }
        }
        // ---- MFMA: out_tile = qn(64x64) @ ctx(64x64)
        f32x4 acc[4][4];
        #pragma unroll
        for (int i = 0; i < 4; ++i)
            #pragma unroll
            for (int j = 0; j < 4; ++j) acc[i][j] = (f32x4)(0.0f);
        #pragma unroll
        for (int ks = 0; ks < 2; ++ks) {
            const int koff = ks * 32 + quad * 8;
            bf16x8 af[4], bfr[4];
            #pragma unroll
            for (int mt = 0; mt < 4; ++mt)
                af[mt] = *(const bf16x8*)(qb + (mt*16 + l15)*LDT + koff);
            #pragma unroll
            for (int nt = 0; nt < 4; ++nt)
                bfr[nt] = *(const bf16x8*)(ctxT_s + (nt*16 + l15)*LDT + koff);
            #pragma unroll
            for (int mt = 0; mt < 4; ++mt)
                #pragma unroll
                for (int nt = 0; nt < 4; ++nt)
                    acc[mt][nt] = __builtin_amdgcn_mfma_f32_16x16x32_bf16(
                        af[mt], bfr[nt], acc[mt][nt], 0, 0, 0);
        }
        // ---- store: C/D layout col = l15, row = quad*4 + reg
        float* ob = out + ((size_t)b * Nn + rbase) * Dn;
        #pragma unroll
        for (int mt = 0; mt < 4; ++mt)
            #pragma unroll
            for (int i = 0; i < 4; ++i) {
                const int r = mt*16 + quad*4 + i;
                #pragma unroll
                for (int nt = 0; nt < 4; ++nt)
                    ob[(size_t)r * Dn + nt*16 + l15] = acc[mt][nt][i];
            }
    }
}

// ---------------------------------------------------------------------------
extern "C" void kernel_launch(void* const* d_in, const int* in_sizes, int n_in,
                              void* d_out, int out_size, void* d_ws, size_t ws_size,
                              hipStream_t stream) {
    const float* q = (const float*)d_in[0];
    const float* k = (const float*)d_in[1];
    const float* v = (const float*)d_in[2];
    float* outp = (float*)d_out;

    // ws layout: partials [Bn*SB][4096] fp32 (16 MB), then ctxT [Bn][4096] fp32 (512 KB)
    float* partial = (float*)d_ws;
    float* ctx = partial + (size_t)Bn * SB * 4096;

    ctx_partial_kernel<<<dim3(Bn * SB), dim3(256), 0, stream>>>(k, v, partial);
    ctx_reduce_kernel<<<dim3((Bn * 4096) / 256), dim3(256), 0, stream>>>(partial, ctx);
    attn_out_kernel<<<dim3(Bn * SB), dim3(256), 0, stream>>>(q, ctx, outp);
}